// Round 1
// baseline (161.542 us; speedup 1.0000x reference)
//
#include <hip/hip_runtime.h>

#define B 2
#define N 16384
#define NPOINT 4096
#define C 64
#define NSAMPLE 32

// Threshold exactly as the JAX/numpy reference sees it:
// float32(double(0.1)*double(0.1)) = 0.009999999776482582f
// (NOT 0.1f*0.1f which is one ulp higher)
__device__ __forceinline__ float r2_thresh() { return (float)(0.1 * 0.1); }

// ---------------- Kernel 1: ball query, one wave (64 lanes) per query ----------------
__global__ void __launch_bounds__(256) ball_query_kernel(
    const float* __restrict__ xyz,      // (B, N, 3)
    const float* __restrict__ new_xyz,  // (B, NPOINT, 3)
    int* __restrict__ idx_out)          // (B, NPOINT, NSAMPLE)
{
    const int gtid = blockIdx.x * blockDim.x + threadIdx.x;
    const int wave = gtid >> 6;
    const int lane = threadIdx.x & 63;
    if (wave >= B * NPOINT) return;

    const int b = wave / NPOINT;
    const int j = wave - b * NPOINT;

    const float cx = new_xyz[(b * NPOINT + j) * 3 + 0];
    const float cy = new_xyz[(b * NPOINT + j) * 3 + 1];
    const float cz = new_xyz[(b * NPOINT + j) * 3 + 2];

    const float* __restrict__ xb = xyz + (size_t)b * N * 3;
    int* __restrict__ out = idx_out + ((size_t)b * NPOINT + j) * NSAMPLE;

    const float r2 = r2_thresh();

    int cnt = 0;        // wave-uniform (derived from ballot)
    int first_idx = 0;  // wave-uniform

    for (int base = 0; base < N; base += 64) {
        const int i = base + lane;
        float x = xb[i * 3 + 0];
        float y = xb[i * 3 + 1];
        float z = xb[i * 3 + 2];

        float d2;
        {
#pragma clang fp contract(off)
            float dx = x - cx;
            float dy = y - cy;
            float dz = z - cz;
            d2 = dx * dx + dy * dy + dz * dz;  // matches numpy: ((dx^2+dy^2)+dz^2), no FMA
        }
        const bool inball = d2 < r2;
        const unsigned long long mask = __ballot(inball);

        if (inball) {
            // rank of this lane among set bits below it -> preserves original point order
            const int rank = __popcll(mask & ((1ull << lane) - 1ull));
            const int pos = cnt + rank;
            if (pos < NSAMPLE) out[pos] = i;
        }
        if (cnt == 0 && mask != 0ull) {
            first_idx = base + __builtin_ctzll(mask);
        }
        cnt += __popcll(mask);
        if (cnt >= NSAMPLE) break;  // wave-uniform branch
    }

    // pad remaining slots with first in-ball index (0 if ball empty)
    if (cnt < NSAMPLE) {
        if (cnt == 0) first_idx = 0;
        for (int pos = cnt + lane; pos < NSAMPLE; pos += 64) out[pos] = first_idx;
    }
}

// ---------------- Kernel 2: grouping (gather + subtract center) ----------------
// Block = 256 threads = 8 queries x 32 samples. Grid = (NPOINT/8, B).
__global__ void __launch_bounds__(256) group_kernel(
    const float* __restrict__ xyz,      // (B, N, 3)
    const float* __restrict__ new_xyz,  // (B, NPOINT, 3)
    const float* __restrict__ feat,     // (B, C, N)
    const int* __restrict__ idx_arr,    // (B, NPOINT, NSAMPLE)
    float* __restrict__ out)            // (B, 3+C, NPOINT, NSAMPLE)
{
    const int t = threadIdx.x;
    const int s = t & 31;        // sample slot
    const int jl = t >> 5;       // 0..7 local query
    const int j = blockIdx.x * 8 + jl;
    const int b = blockIdx.y;

    const int id = idx_arr[((size_t)b * NPOINT + j) * NSAMPLE + s];

    // grouped_xyz - center
    const float px = xyz[((size_t)b * N + id) * 3 + 0] - new_xyz[((size_t)b * NPOINT + j) * 3 + 0];
    const float py = xyz[((size_t)b * N + id) * 3 + 1] - new_xyz[((size_t)b * NPOINT + j) * 3 + 1];
    const float pz = xyz[((size_t)b * N + id) * 3 + 2] - new_xyz[((size_t)b * NPOINT + j) * 3 + 2];

    const size_t plane = (size_t)NPOINT * NSAMPLE;               // 131072
    const size_t obase = (size_t)b * (3 + C) * plane + (size_t)j * NSAMPLE + s;

    out[obase + 0 * plane] = px;
    out[obase + 1 * plane] = py;
    out[obase + 2 * plane] = pz;

    const float* __restrict__ fb = feat + (size_t)b * C * N;
#pragma unroll 8
    for (int c = 0; c < C; ++c) {
        out[obase + (size_t)(3 + c) * plane] = fb[(size_t)c * N + id];
    }
}

extern "C" void kernel_launch(void* const* d_in, const int* in_sizes, int n_in,
                              void* d_out, int out_size, void* d_ws, size_t ws_size,
                              hipStream_t stream) {
    const float* xyz     = (const float*)d_in[0];  // (B, N, 3)
    const float* new_xyz = (const float*)d_in[1];  // (B, NPOINT, 3)
    const float* feat    = (const float*)d_in[2];  // (B, C, N)
    float* out = (float*)d_out;
    int* idx_ws = (int*)d_ws;  // B*NPOINT*NSAMPLE ints = 1 MB

    // Kernel 1: one wave per query; 8192 waves -> 2048 blocks of 256 (4 waves each)
    {
        const int waves = B * NPOINT;
        const int blocks = (waves * 64) / 256;
        ball_query_kernel<<<blocks, 256, 0, stream>>>(xyz, new_xyz, idx_ws);
    }
    // Kernel 2: grouping
    {
        dim3 grid(NPOINT / 8, B);
        group_kernel<<<grid, 256, 0, stream>>>(xyz, new_xyz, feat, idx_ws, out);
    }
}